// Round 1
// baseline (301.580 us; speedup 1.0000x reference)
//
#include <hip/hip_runtime.h>

// NHWC conv 3x3 stride-1 SAME: x[16,128,128,64] f32, w[3,3,64,128] f32,
// bias[128] f32 -> out[16,128,128,128] f32.
// Implicit GEMM, bf16 MFMA 16x16x32.
// Round 3: persistent 4-row blocks (grid 512 = 2 resident/CU), rotating
// 4-slot LDS row buffer, pipelined staging (issue loads early, cvt+ds_write
// after vmcnt(0)), raw s_barrier + counted waits instead of __syncthreads
// in the main loop. Out-of-range rows are zero-filled slots (branch-free taps).

#define HH 128
#define WW 128
#define CIN 64
#define COUT 128
#define HS 4                       // output rows per block

typedef __attribute__((ext_vector_type(8))) short v8s;   // 8 bf16 = 16 B
typedef __attribute__((ext_vector_type(4))) float v4f;   // MFMA C/D

#define ROW_CHUNKS 1040            // 130 px * 8 chunks(16B) per px
#define WS_NEEDED  (9u * CIN * COUT * 2u)   // transposed bf16 weights

static __device__ __forceinline__ unsigned short f2bf(float f) {
    unsigned int u = __float_as_uint(f);
    unsigned int r = (u + 0x7fffu + ((u >> 16) & 1u)) >> 16;   // RNE
    return (unsigned short)r;
}

// ---- pre-pass: w[tap][ci][co] fp32 -> w_t[tap][co][ci] bf16 ----
__global__ __launch_bounds__(256) void cvt_w(const float* __restrict__ wgt,
                                             unsigned short* __restrict__ wt) {
    int idx = blockIdx.x * 256 + threadIdx.x;   // < 9*64*128 = 73728
    if (idx >= 9 * CIN * COUT) return;
    int co  = idx & (COUT - 1);
    int ci  = (idx >> 7) & (CIN - 1);
    int tap = idx >> 13;
    wt[(tap * COUT + co) * CIN + ci] = f2bf(wgt[idx]);
}

// ---- main: persistent-row implicit-GEMM MFMA conv ----
__global__ __launch_bounds__(256, 2) void conv_mfma(
    const float* __restrict__ x,            // fp32 [16,128,128,64]
    const unsigned short* __restrict__ wt,  // bf16 [9,128,64] (tap,co,ci)
    const float* __restrict__ bias,
    float* __restrict__ out) {
    __shared__ v8s smem[4 * ROW_CHUNKS];    // 4 rotating row slots, 66,560 B

    // XCD-aware remap for 512 blocks: each XCD gets 2 whole images
    int bid = blockIdx.x;                   // 0..511
    int logical = ((bid & 7) << 6) | (bid >> 3);
    int hg = logical & 31;                  // h-group (4 rows each)
    int n  = logical >> 5;                  // image
    int h0 = hg * HS;

    int tid  = threadIdx.x;
    int lane = tid & 63;
    int wid  = tid >> 6;           // 0..3
    int wi = wid >> 1;             // pixel half (0/1)
    int wj = wid & 1;              // cout half (0/1)
    int l15  = lane & 15;
    int quad = lane >> 4;
    int pixelL = wi * 64 + l15;    // lane's base pixel (m index)

    const float* xn = x + (size_t)n * HH * WW * CIN;

    // ---- zero the 1-px borders of all 4 slots (stay zero across reuse) ----
    if (tid < 64) {
        int slot = tid >> 4, k = tid & 15;
        int c = (k < 8) ? k : (1024 + k);          // 0..7 or 1032..1039
        smem[slot * ROW_CHUNKS + c] = (v8s)(short)0;
    }

    // ---- prologue: slots 0..2 = input rows h0-1 .. h0+1 ----
    #pragma unroll
    for (int s = 0; s < 3; ++s) {
        int ih = h0 + s - 1;
        v8s* dst = smem + s * ROW_CHUNKS;
        if (ih >= 0) {                              // block-uniform (ih<HH always)
            const float* rowf = xn + (size_t)ih * WW * CIN;
            #pragma unroll
            for (int k = 0; k < 4; ++k) {
                int c = 8 + tid + (k << 8);        // data chunk 8..1031
                const float* p = rowf + (size_t)(c - 8) * 8;
                float4 a = *(const float4*)p;
                float4 b = *(const float4*)(p + 4);
                v8s ch;
                ch[0] = (short)f2bf(a.x); ch[1] = (short)f2bf(a.y);
                ch[2] = (short)f2bf(a.z); ch[3] = (short)f2bf(a.w);
                ch[4] = (short)f2bf(b.x); ch[5] = (short)f2bf(b.y);
                ch[6] = (short)f2bf(b.z); ch[7] = (short)f2bf(b.w);
                dst[c ^ ((c >> 3) & 7)] = ch;      // xor-swizzle within px
            }
        } else {
            #pragma unroll
            for (int k = 0; k < 4; ++k) {
                int c = 8 + tid + (k << 8);
                dst[c ^ ((c >> 3) & 7)] = (v8s)(short)0;
            }
        }
    }
    __syncthreads();

    float bv[4];
    #pragma unroll
    for (int tj = 0; tj < 4; ++tj) bv[tj] = bias[wj * 64 + tj * 16 + l15];

    // ---- main loop: compute row h0+t from slots t,t+1,t+2; prefetch row
    //      h0+t+2 into slot t+3 under the MFMA phase ----
    #pragma unroll 1
    for (int t = 0; t < HS; ++t) {
        bool last = (t == HS - 1);
        int ihn = h0 + t + 2;                      // next input row to stage
        bool inr = (ihn < HH);                     // block-uniform

        // issue staging loads early: they fly under the MFMA phase
        float4 nxt[8];
        if (!last && inr) {
            const float* rowf = xn + (size_t)ihn * WW * CIN;
            #pragma unroll
            for (int k = 0; k < 4; ++k) {
                const float* p = rowf + (size_t)(tid + (k << 8)) * 8;
                nxt[2 * k]     = *(const float4*)p;
                nxt[2 * k + 1] = *(const float4*)(p + 4);
            }
        }

        v4f acc[4][4];
        #pragma unroll
        for (int i = 0; i < 4; ++i)
            #pragma unroll
            for (int j = 0; j < 4; ++j) acc[i][j] = (v4f)0.f;

        #pragma unroll
        for (int dh = 0; dh < 3; ++dh) {
            const v8s* srow = smem + ((t + dh) & 3) * ROW_CHUNKS;
            #pragma unroll
            for (int dw = 0; dw < 3; ++dw) {
                const unsigned short* wtap = wt + (dh * 3 + dw) * COUT * CIN;
                #pragma unroll
                for (int kc = 0; kc < 2; ++kc) {
                    v8s bfrag[4];
                    #pragma unroll
                    for (int tt = 0; tt < 4; ++tt) {
                        int co = wj * 64 + tt * 16 + l15;
                        bfrag[tt] = *(const v8s*)(wtap + co * CIN + kc * 32 + quad * 8);
                    }
                    v8s afrag[4];
                    #pragma unroll
                    for (int tt = 0; tt < 4; ++tt) {
                        int pl = pixelL + tt * 16 + dw;   // 0..129, borders 0
                        int c  = pl * 8 + kc * 4 + quad;
                        afrag[tt] = srow[c ^ (pl & 7)];
                    }
                    #pragma unroll
                    for (int ti = 0; ti < 4; ++ti)
                        #pragma unroll
                        for (int tj = 0; tj < 4; ++tj)
                            acc[ti][tj] = __builtin_amdgcn_mfma_f32_16x16x32_bf16(
                                afrag[ti], bfrag[tj], acc[ti][tj], 0, 0, 0);
                }
            }
        }

        // land the staged row: wait loads, convert, LDS-write
        if (!last) {
            asm volatile("s_waitcnt vmcnt(0)" ::: "memory");
            v8s* dst = smem + ((t + 3) & 3) * ROW_CHUNKS;
            if (inr) {
                #pragma unroll
                for (int k = 0; k < 4; ++k) {
                    int c = 8 + tid + (k << 8);
                    float4 a = nxt[2 * k], b = nxt[2 * k + 1];
                    v8s ch;
                    ch[0] = (short)f2bf(a.x); ch[1] = (short)f2bf(a.y);
                    ch[2] = (short)f2bf(a.z); ch[3] = (short)f2bf(a.w);
                    ch[4] = (short)f2bf(b.x); ch[5] = (short)f2bf(b.y);
                    ch[6] = (short)f2bf(b.z); ch[7] = (short)f2bf(b.w);
                    dst[c ^ ((c >> 3) & 7)] = ch;
                }
            } else {
                #pragma unroll
                for (int k = 0; k < 4; ++k) {
                    int c = 8 + tid + (k << 8);
                    dst[c ^ ((c >> 3) & 7)] = (v8s)(short)0;
                }
            }
        }

        // store output row h0+t (after ds_write so the next barrier's
        // lgkm wait doesn't serialize on these vmem stores)
        float* orow = out + ((size_t)(n * HH + (h0 + t))) * WW * COUT;
        #pragma unroll
        for (int ti = 0; ti < 4; ++ti) {
            #pragma unroll
            for (int r = 0; r < 4; ++r) {
                int p = wi * 64 + ti * 16 + quad * 4 + r;   // C/D: row=quad*4+reg
                float* op = orow + (size_t)p * COUT + wj * 64 + l15;
                #pragma unroll
                for (int tj = 0; tj < 4; ++tj)
                    op[tj * 16] = acc[ti][tj][r] + bv[tj];
            }
        }

        if (!last) {
            asm volatile("s_waitcnt lgkmcnt(0)" ::: "memory");  // ds_writes visible
            __builtin_amdgcn_sched_barrier(0);
            __builtin_amdgcn_s_barrier();
            __builtin_amdgcn_sched_barrier(0);
        }
    }
}

// ---- fallback (direct conv) if workspace is too small ----
__global__ __launch_bounds__(256) void conv3x3_direct(
    const float* __restrict__ x, const float* __restrict__ wgt,
    const float* __restrict__ bias, float* __restrict__ out) {
    int idx = blockIdx.x * 256 + threadIdx.x;
    int co = idx & (COUT - 1);
    int w  = (idx >> 7) & (WW - 1);
    int h  = (idx >> 14) & (HH - 1);
    int n  = idx >> 21;
    float acc = bias[co];
    #pragma unroll
    for (int kh = 0; kh < 3; ++kh) {
        int ih = h + kh - 1;
        if (ih < 0 || ih >= HH) continue;
        #pragma unroll
        for (int kw = 0; kw < 3; ++kw) {
            int iw = w + kw - 1;
            if (iw < 0 || iw >= WW) continue;
            const float* xp = x + (((size_t)(n * HH + ih) * WW + iw) * CIN);
            const float* wp = wgt + ((size_t)((kh * 3 + kw) * CIN)) * COUT + co;
            #pragma unroll 8
            for (int ci = 0; ci < CIN; ++ci)
                acc = fmaf(xp[ci], wp[(size_t)ci * COUT], acc);
        }
    }
    out[idx] = acc;
}

extern "C" void kernel_launch(void* const* d_in, const int* in_sizes, int n_in,
                              void* d_out, int out_size, void* d_ws, size_t ws_size,
                              hipStream_t stream) {
    const float* x    = (const float*)d_in[0];
    const float* wgt  = (const float*)d_in[1];
    const float* bias = (const float*)d_in[2];
    float* out = (float*)d_out;

    if (ws_size < (size_t)WS_NEEDED) {
        int blocks = (out_size + 255) / 256;
        conv3x3_direct<<<blocks, 256, 0, stream>>>(x, wgt, bias, out);
        return;
    }

    unsigned short* wt = (unsigned short*)d_ws;
    cvt_w<<<(9 * CIN * COUT + 255) / 256, 256, 0, stream>>>(wgt, wt);
    conv_mfma<<<16 * HH / HS, 256, 0, stream>>>(x, wt, bias, out);
}